// Round 6
// baseline (114.704 us; speedup 1.0000x reference)
//
#include <hip/hip_runtime.h>

// ParallelMagLoss: per-row margin-substituted log-softmax CE + one_hot emit.
// Outputs (flat f32): [0]=loss.mean(), [1]=loss_g, [2..]=one_hot (B*C).
//
// R6: single fused kernel. R4 body (aligned-f4 zero-fill, max-free 4-way
// unrolled exp-sum) + last-block finalize (atomic counter in ws, zeroed per
// call via 4-byte hipMemsetAsync). Removes the serialized 1-block finalize
// launch (~4-5 us of the 33.9 us total).

#define UA2_INV (1.0f / 12100.0f)   // 1 / (110^2)
#define SEG 8                        // segments per row (power of 2)
#define SEG_SHIFT 3

typedef float v4f __attribute__((ext_vector_type(4)));
typedef float v2f __attribute__((ext_vector_type(2)));

__device__ __forceinline__ void fix_target(float4& v, int c, int t4, int kt4,
                                           float ctm_t) {
    if (c == t4) {   // taken for at most one (thread, iteration) per row
        v.x = (kt4 == 0) ? ctm_t : v.x;
        v.y = (kt4 == 1) ? ctm_t : v.y;
        v.z = (kt4 == 2) ? ctm_t : v.z;
        v.w = (kt4 == 3) ? ctm_t : v.w;
    }
}

__device__ __forceinline__ float exp_sum4(const float4& v) {
    return (__expf(v.x) + __expf(v.y)) + (__expf(v.z) + __expf(v.w));
}

__global__ __launch_bounds__(256) void magloss_fused_kernel(
    const float* __restrict__ ct,     // cos_theta   [B,C]
    const float* __restrict__ ctm,    // cos_theta_m [B,C] (target col only)
    const int*   __restrict__ target, // [B]
    const float* __restrict__ x_norm, // [B]
    float*       __restrict__ out,    // d_out: [0]=loss,[1]=loss_g,[2..]=one_hot
    float*       __restrict__ part,   // ws: [B*SEG] partial exp-sums
    float*       __restrict__ ctmt,   // ws: [B] staged cos_theta_m[target]
    unsigned*    __restrict__ counter,// ws: zeroed per call
    int B, int C)
{
    const int bid = blockIdx.x;
    const int row = bid >> SEG_SHIFT;
    const int seg = bid & (SEG - 1);
    const size_t base = (size_t)row * (size_t)C;
    const int t = target[row];
    const float ctm_t = ctm[base + (size_t)t];

    if (seg == 0 && threadIdx.x == 0) ctmt[row] = ctm_t;

    // ---------- one_hot zero-fill: aligned float4 (plain stores) ----------
    // one_hot row base = out + 2 + row*C; element 2 of the row is 16B-aligned
    // (C % 4 == 0, d_out 16B-aligned).
    float* oh = out + 2 + base;
    v4f* __restrict__ oh4 = (v4f*)(oh + 2);
    const int K   = (C - 2) >> 2;                  // aligned float4 units
    const int ups = (K + SEG - 1) >> SEG_SHIFT;
    const int u0 = seg * ups;
    const int u1 = min(u0 + ups, K);
    const int ut = (t >= 2) ? ((t - 2) >> 2) : -1; // unit holding target
    const int kt = (t - 2) & 3;

    for (int u = u0 + (int)threadIdx.x; u < u1; u += 256) {
        v4f z = {0.f, 0.f, 0.f, 0.f};
        if (u == ut) {
            z.x = (kt == 0) ? 1.f : 0.f;
            z.y = (kt == 1) ? 1.f : 0.f;
            z.z = (kt == 2) ? 1.f : 0.f;
            z.w = (kt == 3) ? 1.f : 0.f;
        }
        oh4[u] = z;
    }
    if (seg == 0 && threadIdx.x == 1) {            // front peel: elements 0,1
        v2f f;
        f.x = (t == 0) ? 1.f : 0.f;
        f.y = (t == 1) ? 1.f : 0.f;
        *(v2f*)oh = f;                              // 8B-aligned
    }
    if (seg == SEG - 1) {                           // tail: [2+4K, C)
        for (int j = 2 + 4 * K + (int)threadIdx.x; j < C; j += 256)
            oh[j] = (j == t) ? 1.f : 0.f;
    }

    // ---------- max-free exp-sum over this segment ----------
    const int nchunk = C >> 2;
    const int cps = (nchunk + SEG - 1) >> SEG_SHIFT;
    const int c0 = seg * cps;
    const int c1 = min(c0 + cps, nchunk);
    const int t4  = t >> 2;
    const int kt4 = t & 3;

    const float4* __restrict__ ct4 = (const float4*)(ct + base);

    float s0 = 0.f, s1 = 0.f, s2 = 0.f, s3 = 0.f;
    int c = c0 + (int)threadIdx.x;
    for (; c + 768 < c1; c += 1024) {
        float4 a = ct4[c];
        float4 b = ct4[c + 256];
        float4 d = ct4[c + 512];
        float4 e = ct4[c + 768];
        fix_target(a, c,       t4, kt4, ctm_t);
        fix_target(b, c + 256, t4, kt4, ctm_t);
        fix_target(d, c + 512, t4, kt4, ctm_t);
        fix_target(e, c + 768, t4, kt4, ctm_t);
        s0 += exp_sum4(a);
        s1 += exp_sum4(b);
        s2 += exp_sum4(d);
        s3 += exp_sum4(e);
    }
    for (; c < c1; c += 256) {
        float4 a = ct4[c];
        fix_target(a, c, t4, kt4, ctm_t);
        s0 += exp_sum4(a);
    }
    // scalar read tail (C % 4 != 0) — no-op for C=100000
    if (seg == SEG - 1) {
        for (int j = (nchunk << 2) + (int)threadIdx.x; j < C; j += 256) {
            const float v = (j == t) ? ctm_t : ct[base + (size_t)j];
            s1 += __expf(v);
        }
    }

    float s = (s0 + s1) + (s2 + s3);

    #pragma unroll
    for (int off = 32; off; off >>= 1)
        s += __shfl_xor(s, off);

    __shared__ float ss[4];
    const int wave = threadIdx.x >> 6;
    const int lane = threadIdx.x & 63;
    if (lane == 0) ss[wave] = s;
    __syncthreads();

    // ---------- part store + last-block finalize ----------
    __shared__ unsigned last;
    if (threadIdx.x == 0) {
        part[bid] = (ss[0] + ss[1]) + (ss[2] + ss[3]);
        __threadfence();                  // release: part visible device-wide
        last = atomicAdd(counter, 1u);
    }
    __syncthreads();

    if (last == (unsigned)(gridDim.x - 1)) {
        __threadfence();                  // acquire: see all parts
        const int i = threadIdx.x;
        float l = 0.f, g = 0.f;
        for (int r = i; r < B; r += 256) {
            const float* p = part + (r << SEG_SHIFT);
            float S = 0.f;
            #pragma unroll
            for (int sgi = 0; sgi < SEG; ++sgi) S += p[sgi];
            l += __logf(S) - ctmt[r];     // row loss (max-free LSE)
            const float xn = x_norm[r];
            g += xn * UA2_INV + 1.0f / xn;
        }
        #pragma unroll
        for (int off = 32; off; off >>= 1) {
            l += __shfl_xor(l, off);
            g += __shfl_xor(g, off);
        }
        __shared__ float sl[4], sg[4];
        if (lane == 0) { sl[wave] = l; sg[wave] = g; }
        __syncthreads();
        if (i == 0) {
            float L = 0.f, G = 0.f;
            #pragma unroll
            for (int w = 0; w < 4; ++w) { L += sl[w]; G += sg[w]; }
            out[0] = L / (float)B;
            out[1] = G / (float)B;
        }
    }
}

extern "C" void kernel_launch(void* const* d_in, const int* in_sizes, int n_in,
                              void* d_out, int out_size, void* d_ws, size_t ws_size,
                              hipStream_t stream) {
    const float* ct  = (const float*)d_in[0];
    const float* ctm = (const float*)d_in[1];
    const float* xn  = (const float*)d_in[2];
    const int*   tg  = (const int*)d_in[3];

    const int B = in_sizes[2];
    const int C = in_sizes[0] / B;

    float* out  = (float*)d_out;
    float* part = (float*)d_ws;                 // B*SEG floats
    float* ctmt = part + B * SEG;               // B floats
    unsigned* counter = (unsigned*)(ctmt + B);  // 1 uint, 4B-aligned

    hipMemsetAsync(counter, 0, sizeof(unsigned), stream);
    magloss_fused_kernel<<<B * SEG, 256, 0, stream>>>(ct, ctm, tg, xn, out,
                                                      part, ctmt, counter, B, C);
}

// Round 7
// 32.805 us; speedup vs baseline: 3.4965x; 3.4965x over previous
//
#include <hip/hip_runtime.h>

// ParallelMagLoss: per-row margin-substituted log-softmax CE + one_hot emit.
// Outputs (flat f32): [0]=loss.mean(), [1]=loss_g, [2..]=one_hot (B*C).
//
// R7: R4 structure (best measured: 33.9us) + phase stagger: odd blocks run
// read-then-write, even blocks write-then-read, so the HBM read and write
// streams overlap continuously instead of executing as synchronized bursts.
// NO device-scope fences (R6 lesson: __threadfence => per-block L2 flush =>
// 5x regression).

#define UA2_INV (1.0f / 12100.0f)   // 1 / (110^2)
#define SEG 8                        // segments per row (power of 2)
#define SEG_SHIFT 3

typedef float v4f __attribute__((ext_vector_type(4)));
typedef float v2f __attribute__((ext_vector_type(2)));

__device__ __forceinline__ void fix_target(float4& v, int c, int t4, int kt4,
                                           float ctm_t) {
    if (c == t4) {   // taken for at most one (thread, iteration) per row
        v.x = (kt4 == 0) ? ctm_t : v.x;
        v.y = (kt4 == 1) ? ctm_t : v.y;
        v.z = (kt4 == 2) ? ctm_t : v.z;
        v.w = (kt4 == 3) ? ctm_t : v.w;
    }
}

__device__ __forceinline__ float exp_sum4(const float4& v) {
    return (__expf(v.x) + __expf(v.y)) + (__expf(v.z) + __expf(v.w));
}

// one_hot zero-fill for this (row, seg): aligned float4 plain stores.
__device__ __forceinline__ void do_fill(float* __restrict__ oh, int seg, int t,
                                        int C, int tid) {
    v4f* __restrict__ oh4 = (v4f*)(oh + 2);        // 16B-aligned
    const int K   = (C - 2) >> 2;
    const int ups = (K + SEG - 1) >> SEG_SHIFT;
    const int u0 = seg * ups;
    const int u1 = min(u0 + ups, K);
    const int ut = (t >= 2) ? ((t - 2) >> 2) : -1;
    const int kt = (t - 2) & 3;

    for (int u = u0 + tid; u < u1; u += 256) {
        v4f z = {0.f, 0.f, 0.f, 0.f};
        if (u == ut) {
            z.x = (kt == 0) ? 1.f : 0.f;
            z.y = (kt == 1) ? 1.f : 0.f;
            z.z = (kt == 2) ? 1.f : 0.f;
            z.w = (kt == 3) ? 1.f : 0.f;
        }
        oh4[u] = z;
    }
    if (seg == 0 && tid == 1) {                    // front peel: elements 0,1
        v2f f;
        f.x = (t == 0) ? 1.f : 0.f;
        f.y = (t == 1) ? 1.f : 0.f;
        *(v2f*)oh = f;                              // 8B-aligned
    }
    if (seg == SEG - 1) {                           // tail: [2+4K, C)
        for (int j = 2 + 4 * K + tid; j < C; j += 256)
            oh[j] = (j == t) ? 1.f : 0.f;
    }
}

// max-free exp-sum over this (row, seg); returns per-thread partial.
__device__ __forceinline__ float do_read(const float4* __restrict__ ct4,
                                         const float* __restrict__ ct_row,
                                         int seg, int t, int C, int tid,
                                         float ctm_t) {
    const int nchunk = C >> 2;
    const int cps = (nchunk + SEG - 1) >> SEG_SHIFT;
    const int c0 = seg * cps;
    const int c1 = min(c0 + cps, nchunk);
    const int t4  = t >> 2;
    const int kt4 = t & 3;

    float s0 = 0.f, s1 = 0.f, s2 = 0.f, s3 = 0.f;
    int c = c0 + tid;
    for (; c + 768 < c1; c += 1024) {
        float4 a = ct4[c];
        float4 b = ct4[c + 256];
        float4 d = ct4[c + 512];
        float4 e = ct4[c + 768];
        fix_target(a, c,       t4, kt4, ctm_t);
        fix_target(b, c + 256, t4, kt4, ctm_t);
        fix_target(d, c + 512, t4, kt4, ctm_t);
        fix_target(e, c + 768, t4, kt4, ctm_t);
        s0 += exp_sum4(a);
        s1 += exp_sum4(b);
        s2 += exp_sum4(d);
        s3 += exp_sum4(e);
    }
    for (; c < c1; c += 256) {
        float4 a = ct4[c];
        fix_target(a, c, t4, kt4, ctm_t);
        s0 += exp_sum4(a);
    }
    if (seg == SEG - 1) {   // scalar read tail — no-op for C=100000
        for (int j = (nchunk << 2) + tid; j < C; j += 256) {
            const float v = (j == t) ? ctm_t : ct_row[j];
            s1 += __expf(v);
        }
    }
    return (s0 + s1) + (s2 + s3);
}

__global__ __launch_bounds__(256) void magloss_part_kernel(
    const float* __restrict__ ct,     // cos_theta   [B,C]
    const float* __restrict__ ctm,    // cos_theta_m [B,C] (target col only)
    const int*   __restrict__ target, // [B]
    float*       __restrict__ onehot, // d_out + 2   [B,C]
    float*       __restrict__ part,   // ws: [B*SEG] partial exp-sums
    float*       __restrict__ ctmt,   // ws: [B] staged cos_theta_m[target]
    int C)
{
    const int bid = blockIdx.x;
    const int row = bid >> SEG_SHIFT;
    const int seg = bid & (SEG - 1);
    const size_t base = (size_t)row * (size_t)C;
    const int t = target[row];
    const float ctm_t = ctm[base + (size_t)t];
    const int tid = (int)threadIdx.x;

    if (seg == 0 && tid == 0) ctmt[row] = ctm_t;

    const float4* __restrict__ ct4 = (const float4*)(ct + base);
    float* oh = onehot + base;

    // Phase stagger: odd blocks read first, even blocks write first, so the
    // HBM read and write streams are both active at all times.
    float s;
    if (bid & 1) {
        s = do_read(ct4, ct + base, seg, t, C, tid, ctm_t);
        do_fill(oh, seg, t, C, tid);
    } else {
        do_fill(oh, seg, t, C, tid);
        s = do_read(ct4, ct + base, seg, t, C, tid, ctm_t);
    }

    #pragma unroll
    for (int off = 32; off; off >>= 1)
        s += __shfl_xor(s, off);

    __shared__ float ss[4];
    const int wave = tid >> 6;
    const int lane = tid & 63;
    if (lane == 0) ss[wave] = s;
    __syncthreads();

    if (tid == 0)
        part[bid] = (ss[0] + ss[1]) + (ss[2] + ss[3]);
}

__global__ __launch_bounds__(256) void magloss_finalize_kernel(
    const float* __restrict__ part,   // ws [B*SEG] partial sums
    const float* __restrict__ ctmt,   // ws [B]
    const float* __restrict__ x_norm, // [B]
    float*       __restrict__ out,    // d_out (out[0], out[1])
    int B)
{
    const int i = threadIdx.x;
    float l = 0.f, g = 0.f;
    for (int r = i; r < B; r += 256) {
        const float* p = part + (r << SEG_SHIFT);
        float S = 0.f;
        #pragma unroll
        for (int sgi = 0; sgi < SEG; ++sgi) S += p[sgi];
        l += __logf(S) - ctmt[r];             // row loss (max-free LSE)
        const float xn = x_norm[r];
        g += xn * UA2_INV + 1.0f / xn;
    }
    #pragma unroll
    for (int off = 32; off; off >>= 1) {
        l += __shfl_xor(l, off);
        g += __shfl_xor(g, off);
    }
    __shared__ float sl[4], sg[4];
    const int wave = i >> 6;
    const int lane = i & 63;
    if (lane == 0) { sl[wave] = l; sg[wave] = g; }
    __syncthreads();
    if (i == 0) {
        float L = 0.f, G = 0.f;
        #pragma unroll
        for (int w = 0; w < 4; ++w) { L += sl[w]; G += sg[w]; }
        out[0] = L / (float)B;
        out[1] = G / (float)B;
    }
}

extern "C" void kernel_launch(void* const* d_in, const int* in_sizes, int n_in,
                              void* d_out, int out_size, void* d_ws, size_t ws_size,
                              hipStream_t stream) {
    const float* ct  = (const float*)d_in[0];
    const float* ctm = (const float*)d_in[1];
    const float* xn  = (const float*)d_in[2];
    const int*   tg  = (const int*)d_in[3];

    const int B = in_sizes[2];
    const int C = in_sizes[0] / B;

    float* out  = (float*)d_out;
    float* part = (float*)d_ws;          // B*SEG floats = 8 KB
    float* ctmt = part + B * SEG;        // B floats

    magloss_part_kernel<<<B * SEG, 256, 0, stream>>>(ct, ctm, tg, out + 2,
                                                     part, ctmt, C);
    magloss_finalize_kernel<<<1, 256, 0, stream>>>(part, ctmt, xn, out, B);
}